// Round 3
// baseline (17603.694 us; speedup 1.0000x reference)
//
#include <hip/hip_runtime.h>
#include <hip/hip_cooperative_groups.h>

namespace cg = cooperative_groups;

#define Bdim 640
#define Hdim 768
#define PJdim 256
#define Tdim 160
#define NSTEP (Tdim + 2)

typedef _Float16 half8 __attribute__((ext_vector_type(8)));
typedef float floatx4 __attribute__((ext_vector_type(4)));

// ---------------- workspace layout ----------------
// hbuf: 3 layers x B x PJ fp32 (single buffer; gate reads / proj writes barrier-separated)
// mbuf: 3 layers x B x H fp16 (gate -> proj handoff)
// WS:   gate weights fp16, per (l,ht): [kc][nn=256][kk=40] (kk 32..39 zero pad)
// PTc:  P^T fp16 chunked, per l: [kc=24][pj=256][kk=40]
// cst:  3 layers x B x H fp32 (c state, fallback path only)
constexpr size_t HBUF_BYTES = 3ull * Bdim * PJdim * 4;        // 1,966,080
constexpr size_t MBUF_OFF   = HBUF_BYTES;
constexpr size_t MBUF_HALFS = 3ull * Bdim * Hdim;             // 1,474,560
constexpr size_t WS_OFF     = MBUF_OFF + MBUF_HALFS * 2;
constexpr size_t WS0_HALFS  = 12ull * 10 * 256 * 40;          // layer0: K=296 -> 10 chunks
constexpr size_t WS12_HALFS = 12ull * 16 * 256 * 40;          // layers1/2: K=512 -> 16 chunks
constexpr size_t WS_HALFS   = WS0_HALFS + 2 * WS12_HALFS;     // 5,160,960
constexpr size_t PT_OFF     = WS_OFF + WS_HALFS * 2;
constexpr size_t PT_HALFS   = 3ull * 24 * 256 * 40;           // 737,280
constexpr size_t CST_OFF    = PT_OFF + PT_HALFS * 2;
constexpr size_t CST_BYTES  = 3ull * Bdim * Hdim * 4;         // 5,898,240

__device__ __forceinline__ float sigm(float v) { return 1.0f / (1.0f + __expf(-v)); }
__device__ __forceinline__ float tanh_fast(float v) { return 2.0f / (1.0f + __expf(-2.0f * v)) - 1.0f; }

// ---------------- one-time repack: W,P fp32 -> fp16 staging images ----------------
__global__ void repack_kernel(const float* __restrict__ W0, const float* __restrict__ W1,
                              const float* __restrict__ W2, const float* __restrict__ P0,
                              const float* __restrict__ P1, const float* __restrict__ P2,
                              _Float16* __restrict__ WS, _Float16* __restrict__ PT)
{
    size_t idx = (size_t)blockIdx.x * 256 + threadIdx.x;
    if (idx < WS_HALFS) {
        size_t rem; int KC, K; const float* W;
        if (idx < WS0_HALFS)                  { rem = idx;                          KC = 10; K = 296; W = W0; }
        else if (idx < WS0_HALFS + WS12_HALFS){ rem = idx - WS0_HALFS;              KC = 16; K = 512; W = W1; }
        else                                  { rem = idx - WS0_HALFS - WS12_HALFS; KC = 16; K = 512; W = W2; }
        int kk = (int)(rem % 40); size_t r2 = rem / 40;
        int nn = (int)(r2 % 256); size_t r3 = r2 / 256;
        int kc = (int)(r3 % KC);  int ht = (int)(r3 / KC);
        float v = 0.0f;
        int k = kc * 32 + kk;
        if (kk < 32 && k < K) {
            int ng = (nn >> 6) * Hdim + ht * 64 + (nn & 63);   // gate-major column index
            v = W[(size_t)k * (4 * Hdim) + ng];
        }
        WS[idx] = (_Float16)v;
    } else if (idx < WS_HALFS + PT_HALFS) {
        size_t i2 = idx - WS_HALFS;
        int l = (int)(i2 / (24 * 256 * 40)); size_t rem = i2 % (24 * 256 * 40);
        int kk = (int)(rem % 40); size_t r2 = rem / 40;
        int nn = (int)(r2 % 256); int kc = (int)(r2 / 256);
        const float* P = (l == 0) ? P0 : (l == 1) ? P1 : P2;
        float v = (kk < 32) ? P[(size_t)(kc * 32 + kk) * PJdim + nn] : 0.0f;
        PT[i2] = (_Float16)v;
    }
}

// ---------------- gate cell body: one (l,ht,bt) task, one timestep ----------------
__device__ __forceinline__ void gate_body(
    const float* __restrict__ xt, const _Float16* __restrict__ Wslab, int KC, int l,
    const float* __restrict__ hL, const float* __restrict__ hLm,
    _Float16* __restrict__ mL, int b0r,
    float bi, float bj, float bff, float bo,
    float (&c)[16],
    _Float16* __restrict__ Alds, _Float16* __restrict__ Wlds, _Float16* __restrict__ Mlds,
    int tid)
{
    const int wv = tid >> 6, lane = tid & 63, qd = lane >> 4, ln = lane & 15;
    const int arow = tid >> 2, kw = (tid & 3) * 8;
    const int gb = b0r + arow;
    const floatx4 fz = {0.f, 0.f, 0.f, 0.f};
    floatx4 acc[16];                                  // [ar*4 + gate]
#pragma unroll
    for (int i = 0; i < 16; i++) acc[i] = fz;

    for (int kc = 0; kc < KC; ++kc) {
        __syncthreads();
        // stage A chunk [64][32] fp32 -> fp16 (all source windows 16B-aligned)
        {
            int kg = kc * 32 + kw;
            const float* src = nullptr;
            if (l == 0) {
                if (kg < 40)       src = xt + (size_t)gb * 40 + kg;
                else if (kg < 296) src = hL + (size_t)gb * PJdim + (kg - 40);
            } else {
                src = (kg < 256) ? hLm + (size_t)gb * PJdim + kg
                                 : hL + (size_t)gb * PJdim + (kg - 256);
            }
            half8 hv;
            if (src) {
                const float4 u = ((const float4*)src)[0];
                const float4 w = ((const float4*)src)[1];
                hv[0] = (_Float16)u.x; hv[1] = (_Float16)u.y; hv[2] = (_Float16)u.z; hv[3] = (_Float16)u.w;
                hv[4] = (_Float16)w.x; hv[5] = (_Float16)w.y; hv[6] = (_Float16)w.z; hv[7] = (_Float16)w.w;
            } else {
#pragma unroll
                for (int e = 0; e < 8; e++) hv[e] = (_Float16)0.f;
            }
            *(half8*)&Alds[arow * 40 + kw] = hv;
        }
        // stage W chunk: flat contiguous 20480 B (global image == LDS image)
        {
            const half8* gsrc = (const half8*)(Wslab + (size_t)kc * 10240);
            half8* ldst = (half8*)Wlds;
#pragma unroll
            for (int i = 0; i < 5; i++)
                ldst[tid + 256 * i] = gsrc[tid + 256 * i];
        }
        __syncthreads();
        // wave wv: all 64 rows x (4 gates x 16 hcols at wv*16) -> 4A + 4B frag reads, 16 MFMA
        half8 a0 = *(const half8*)&Alds[(0 * 16 + ln) * 40 + qd * 8];
        half8 a1 = *(const half8*)&Alds[(1 * 16 + ln) * 40 + qd * 8];
        half8 a2 = *(const half8*)&Alds[(2 * 16 + ln) * 40 + qd * 8];
        half8 a3 = *(const half8*)&Alds[(3 * 16 + ln) * 40 + qd * 8];
#pragma unroll
        for (int gg = 0; gg < 4; ++gg) {
            half8 bfr = *(const half8*)&Wlds[(gg * 64 + wv * 16 + ln) * 40 + qd * 8];
            acc[0 * 4 + gg] = __builtin_amdgcn_mfma_f32_16x16x32_f16(a0, bfr, acc[0 * 4 + gg], 0, 0, 0);
            acc[1 * 4 + gg] = __builtin_amdgcn_mfma_f32_16x16x32_f16(a1, bfr, acc[1 * 4 + gg], 0, 0, 0);
            acc[2 * 4 + gg] = __builtin_amdgcn_mfma_f32_16x16x32_f16(a2, bfr, acc[2 * 4 + gg], 0, 0, 0);
            acc[3 * 4 + gg] = __builtin_amdgcn_mfma_f32_16x16x32_f16(a3, bfr, acc[3 * 4 + gg], 0, 0, 0);
        }
    }

    // elementwise LSTM update (i,j,f,o in-lane)
#pragma unroll
    for (int ar = 0; ar < 4; ++ar) {
#pragma unroll
        for (int r = 0; r < 4; ++r) {
            float zi = acc[ar * 4 + 0][r] + bi;
            float zj = acc[ar * 4 + 1][r] + bj;
            float zf = acc[ar * 4 + 2][r] + bff;
            float zo = acc[ar * 4 + 3][r] + bo;
            float cn = sigm(zf) * c[ar * 4 + r] + sigm(zi) * tanh_fast(zj);
            c[ar * 4 + r] = cn;
            float m = sigm(zo) * tanh_fast(cn);
            Mlds[(ar * 16 + qd * 4 + r) * 72 + wv * 16 + ln] = (_Float16)m;
        }
    }
    __syncthreads();
    // coalesced m -> global fp16 (mL pre-offset by (l,b0r,h0))
    {
        int row = tid >> 2, coff = (tid & 3) * 16;
        half8 v0 = *(const half8*)&Mlds[row * 72 + coff];
        half8 v1 = *(const half8*)&Mlds[row * 72 + coff + 8];
        _Float16* dst = mL + (size_t)row * Hdim + coff;
        *(half8*)dst = v0;
        *(half8*)(dst + 8) = v1;
    }
}

// ---------------- projection body: [64 rows x 64 pj-cols], full K=768, no atomics ----------
__device__ __forceinline__ void proj_body(
    const _Float16* __restrict__ msrc,   // mbuf + (pl*B + pb0r)*H
    const _Float16* __restrict__ Pbase,  // PTc + pl*24*10240 + cq*2560
    float* __restrict__ hdst,            // hbuf + pl*B*PJ
    int pb0r, int cq,
    _Float16* __restrict__ Alds, _Float16* __restrict__ Wlds, int tid)
{
    const int wv = tid >> 6, lane = tid & 63, qd = lane >> 4, ln = lane & 15;
    const int arow = tid >> 2, kw = (tid & 3) * 8;
    const floatx4 fz = {0.f, 0.f, 0.f, 0.f};
    floatx4 pacc[4];
#pragma unroll
    for (int i = 0; i < 4; i++) pacc[i] = fz;

    for (int kc = 0; kc < 24; ++kc) {
        __syncthreads();
        *(half8*)&Alds[arow * 40 + kw] =
            *(const half8*)(msrc + (size_t)arow * Hdim + kc * 32 + kw);
        {
            const half8* pg = (const half8*)(Pbase + (size_t)kc * 10240);
            half8* wd = (half8*)Wlds;
            wd[tid] = pg[tid];
            if (tid < 64) wd[256 + tid] = pg[256 + tid];
        }
        __syncthreads();
        half8 af = *(const half8*)&Alds[(wv * 16 + ln) * 40 + qd * 8];
#pragma unroll
        for (int f = 0; f < 4; ++f) {
            half8 bfr = *(const half8*)&Wlds[(f * 16 + ln) * 40 + qd * 8];
            pacc[f] = __builtin_amdgcn_mfma_f32_16x16x32_f16(af, bfr, pacc[f], 0, 0, 0);
        }
    }
#pragma unroll
    for (int f = 0; f < 4; ++f)
#pragma unroll
        for (int r = 0; r < 4; ++r)
            hdst[(size_t)(pb0r + wv * 16 + qd * 4 + r) * PJdim + cq * 64 + f * 16 + ln]
                = pacc[f][r];
}

// ---------------- persistent cooperative kernel (primary path) ----------------
__global__ __launch_bounds__(256, 1)
void lstm_persist(const float* __restrict__ x,
                  const _Float16* __restrict__ WS, const _Float16* __restrict__ PTc,
                  const float* __restrict__ bias0, const float* __restrict__ bias1,
                  const float* __restrict__ bias2,
                  float* __restrict__ hbuf, _Float16* __restrict__ mbuf,
                  float* __restrict__ out)
{
    cg::grid_group grid = cg::this_grid();
    __shared__ __align__(16) _Float16 Alds[64 * 40];
    __shared__ __align__(16) _Float16 Wlds[256 * 40];
    __shared__ __align__(16) _Float16 Mlds[64 * 72];

    const int tid = threadIdx.x, bid = blockIdx.x;
    const int wv = tid >> 6, lane = tid & 63, ln = lane & 15;

    // ---- gate task 1 (tau = bid), optional task 2 (tau = 256 + bid, bid < 104)
    const int g1 = bid % 36, bt1 = bid / 36;
    const int l1 = g1 / 12, ht1 = g1 % 12, b0r1 = bt1 * 64, h01 = ht1 * 64;
    const int KC1 = (l1 == 0) ? 10 : 16;
    const _Float16* Wslab1 = WS + ((l1 == 0) ? 0ull : (l1 == 1) ? WS0_HALFS : WS0_HALFS + WS12_HALFS)
                                + (size_t)ht1 * KC1 * 10240;
    const float* biasA = (l1 == 0) ? bias0 : (l1 == 1) ? bias1 : bias2;
    const int hc1 = h01 + wv * 16 + ln;
    const float bi1 = biasA[hc1], bj1 = biasA[Hdim + hc1];
    const float bf1 = biasA[2 * Hdim + hc1] + 1.0f, bo1 = biasA[3 * Hdim + hc1];
    const float* hL1  = hbuf + (size_t)l1 * Bdim * PJdim;
    const float* hLm1 = hbuf + (size_t)(l1 > 0 ? l1 - 1 : 0) * Bdim * PJdim;
    _Float16* mL1 = mbuf + ((size_t)l1 * Bdim + b0r1) * Hdim + h01;

    const bool HAS2 = (bid < 104);
    const int t2g = (256 + bid) % 36, bt2 = (256 + bid) / 36;
    const int l2 = t2g / 12, ht2 = t2g % 12, b0r2 = bt2 * 64, h02 = ht2 * 64;
    const int KC2 = (l2 == 0) ? 10 : 16;
    const _Float16* Wslab2 = WS + ((l2 == 0) ? 0ull : (l2 == 1) ? WS0_HALFS : WS0_HALFS + WS12_HALFS)
                                + (size_t)ht2 * KC2 * 10240;
    const float* biasB = (l2 == 0) ? bias0 : (l2 == 1) ? bias1 : bias2;
    const int hc2 = h02 + wv * 16 + ln;
    const float bi2 = biasB[hc2], bj2 = biasB[Hdim + hc2];
    const float bf2 = biasB[2 * Hdim + hc2] + 1.0f, bo2 = biasB[3 * Hdim + hc2];
    const float* hL2  = hbuf + (size_t)l2 * Bdim * PJdim;
    const float* hLm2 = hbuf + (size_t)(l2 > 0 ? l2 - 1 : 0) * Bdim * PJdim;
    _Float16* mL2 = mbuf + ((size_t)l2 * Bdim + b0r2) * Hdim + h02;

    // ---- projection task (bid < 120): (pl, pbt, cq)
    const bool PBLK = (bid < 120);
    const int pl = bid / 40, prr = bid % 40, pbt = prr / 4, cq = prr % 4;
    const int pb0r = pbt * 64;
    const _Float16* msrc  = mbuf + ((size_t)pl * Bdim + pb0r) * Hdim;
    const _Float16* Pbase = PTc + (size_t)pl * 24 * 10240 + (size_t)cq * 2560;
    float* hdstP = hbuf + (size_t)pl * Bdim * PJdim;

    float c1[16], c2[16];
#pragma unroll
    for (int i = 0; i < 16; i++) { c1[i] = 0.f; c2[i] = 0.f; }

    for (int s = 0; s < NSTEP; ++s) {
        {
            const int t1 = s - l1;
            if (t1 >= 0 && t1 < Tdim)
                gate_body(x + (size_t)t1 * Bdim * 40, Wslab1, KC1, l1, hL1, hLm1, mL1, b0r1,
                          bi1, bj1, bf1, bo1, c1, Alds, Wlds, Mlds, tid);
        }
        if (HAS2) {
            const int t2 = s - l2;
            if (t2 >= 0 && t2 < Tdim)
                gate_body(x + (size_t)t2 * Bdim * 40, Wslab2, KC2, l2, hL2, hLm2, mL2, b0r2,
                          bi2, bj2, bf2, bo2, c2, Alds, Wlds, Mlds, tid);
        }
        grid.sync();
        if (PBLK) {
            const int tp = s - pl;
            if (tp >= 0 && tp < Tdim)
                proj_body(msrc, Pbase, hdstP, pb0r, cq, Alds, Wlds, tid);
        }
        grid.sync();
    }

    // ---- fused finalize: L2-normalize h[2] rows
    {
        int row = bid * 4 + wv;
        if (row < Bdim) {
            const float* e = hbuf + (size_t)2 * Bdim * PJdim + (size_t)row * PJdim;
            float4 v = ((const float4*)e)[lane];
            float ss = v.x * v.x + v.y * v.y + v.z * v.z + v.w * v.w;
#pragma unroll
            for (int o = 32; o > 0; o >>= 1) ss += __shfl_xor(ss, o, 64);
            float rs = rsqrtf(fmaxf(ss, 1e-12f));
            float4 ov;
            ov.x = v.x * rs; ov.y = v.y * rs; ov.z = v.z * rs; ov.w = v.w * rs;
            ((float4*)(out + (size_t)row * PJdim))[lane] = ov;
        }
    }
}

// ---------------- fallback path: per-step kernels, c-state in global ----------------
__global__ __launch_bounds__(256, 2)
void gate_step_kernel(const float* __restrict__ x, const _Float16* __restrict__ WS,
                      const float* __restrict__ bias0, const float* __restrict__ bias1,
                      const float* __restrict__ bias2,
                      const float* __restrict__ hbuf, _Float16* __restrict__ mbuf,
                      float* __restrict__ cst, int s)
{
    __shared__ __align__(16) _Float16 Alds[64 * 40];
    __shared__ __align__(16) _Float16 Wlds[256 * 40];
    __shared__ __align__(16) _Float16 Mlds[64 * 72];
    const int tid = threadIdx.x, bid = blockIdx.x;
    const int g = bid % 36, bt = bid / 36;
    const int l = g / 12, ht = g % 12, b0r = bt * 64, h0 = ht * 64;
    const int t = s - l;
    if (t < 0 || t >= Tdim) return;
    const int wv = tid >> 6, lane = tid & 63, qd = lane >> 4, ln = lane & 15;
    const int KC = (l == 0) ? 10 : 16;
    const _Float16* Wslab = WS + ((l == 0) ? 0ull : (l == 1) ? WS0_HALFS : WS0_HALFS + WS12_HALFS)
                               + (size_t)ht * KC * 10240;
    const float* bias = (l == 0) ? bias0 : (l == 1) ? bias1 : bias2;
    const int hcol = h0 + wv * 16 + ln;
    const float bi = bias[hcol], bj = bias[Hdim + hcol];
    const float bff = bias[2 * Hdim + hcol] + 1.0f, bo = bias[3 * Hdim + hcol];
    const float* hL  = hbuf + (size_t)l * Bdim * PJdim;
    const float* hLm = hbuf + (size_t)(l > 0 ? l - 1 : 0) * Bdim * PJdim;
    _Float16* mL = mbuf + ((size_t)l * Bdim + b0r) * Hdim + h0;

    float c[16];
#pragma unroll
    for (int ar = 0; ar < 4; ++ar)
#pragma unroll
        for (int r = 0; r < 4; ++r)
            c[ar * 4 + r] = cst[((size_t)l * Bdim + b0r + ar * 16 + qd * 4 + r) * Hdim + hcol];

    gate_body(x + (size_t)t * Bdim * 40, Wslab, KC, l, hL, hLm, mL, b0r,
              bi, bj, bff, bo, c, Alds, Wlds, Mlds, tid);

#pragma unroll
    for (int ar = 0; ar < 4; ++ar)
#pragma unroll
        for (int r = 0; r < 4; ++r)
            cst[((size_t)l * Bdim + b0r + ar * 16 + qd * 4 + r) * Hdim + hcol] = c[ar * 4 + r];
}

__global__ __launch_bounds__(256, 2)
void proj_step_kernel(const _Float16* __restrict__ mbuf, const _Float16* __restrict__ PTc,
                      float* __restrict__ hbuf, int s)
{
    __shared__ __align__(16) _Float16 Alds[64 * 40];
    __shared__ __align__(16) _Float16 Wlds[64 * 40];
    const int tid = threadIdx.x, bid = blockIdx.x;
    const int pl = bid / 40, prr = bid % 40, pbt = prr / 4, cq = prr % 4;
    const int tp = s - pl;
    if (tp < 0 || tp >= Tdim) return;
    const int pb0r = pbt * 64;
    proj_body(mbuf + ((size_t)pl * Bdim + pb0r) * Hdim,
              PTc + (size_t)pl * 24 * 10240 + (size_t)cq * 2560,
              hbuf + (size_t)pl * Bdim * PJdim, pb0r, cq, Alds, Wlds, tid);
}

__global__ void finalize_fb(const float* __restrict__ hbuf, float* __restrict__ out)
{
    __shared__ float red[4];
    const int b = blockIdx.x, tid = threadIdx.x;
    const float* e = hbuf + (size_t)2 * Bdim * PJdim + (size_t)b * PJdim;
    float v = e[tid];
    float ss = v * v;
#pragma unroll
    for (int o = 32; o > 0; o >>= 1) ss += __shfl_xor(ss, o, 64);
    if ((tid & 63) == 0) red[tid >> 6] = ss;
    __syncthreads();
    float tot = red[0] + red[1] + red[2] + red[3];
    float rs = rsqrtf(fmaxf(tot, 1e-12f));
    out[(size_t)b * PJdim + tid] = v * rs;
}

extern "C" void kernel_launch(void* const* d_in, const int* in_sizes, int n_in,
                              void* d_out, int out_size, void* d_ws, size_t ws_size,
                              hipStream_t stream)
{
    (void)in_sizes; (void)n_in; (void)out_size; (void)ws_size;
    const float* x  = (const float*)d_in[0];
    const float* W0 = (const float*)d_in[1];
    const float* b0 = (const float*)d_in[2];
    const float* P0 = (const float*)d_in[3];
    const float* W1 = (const float*)d_in[4];
    const float* b1 = (const float*)d_in[5];
    const float* P1 = (const float*)d_in[6];
    const float* W2 = (const float*)d_in[7];
    const float* b2 = (const float*)d_in[8];
    const float* P2 = (const float*)d_in[9];

    char* ws = (char*)d_ws;
    float*    hbuf = (float*)(ws);
    _Float16* mbuf = (_Float16*)(ws + MBUF_OFF);
    _Float16* WS   = (_Float16*)(ws + WS_OFF);
    _Float16* PTc  = (_Float16*)(ws + PT_OFF);
    float*    cst  = (float*)(ws + CST_OFF);
    float*    outp = (float*)d_out;

    hipMemsetAsync(hbuf, 0, HBUF_BYTES, stream);
    hipMemsetAsync(cst, 0, CST_BYTES, stream);

    {
        size_t total = WS_HALFS + PT_HALFS;
        int grid = (int)((total + 255) / 256);
        repack_kernel<<<grid, 256, 0, stream>>>(W0, W1, W2, P0, P1, P2, WS, PTc);
    }

    // ---- primary: persistent cooperative kernel (grid = 256 = #CUs)
    int occ = 0;
    hipError_t oe = hipOccupancyMaxActiveBlocksPerMultiprocessor(&occ, lstm_persist, 256, 0);
    bool coop = (oe == hipSuccess && occ >= 1);
    if (coop) {
        void* args[] = { (void*)&x, (void*)&WS, (void*)&PTc,
                         (void*)&b0, (void*)&b1, (void*)&b2,
                         (void*)&hbuf, (void*)&mbuf, (void*)&outp };
        hipError_t le = hipLaunchCooperativeKernel((const void*)lstm_persist,
                                                   dim3(256), dim3(256), args, 0, stream);
        if (le != hipSuccess) { (void)hipGetLastError(); coop = false; }
    }

    // ---- fallback: per-step kernel pairs, c in global
    if (!coop) {
        for (int s = 0; s < NSTEP; ++s) {
            gate_step_kernel<<<360, 256, 0, stream>>>(x, WS, b0, b1, b2, hbuf, mbuf, cst, s);
            proj_step_kernel<<<120, 256, 0, stream>>>(mbuf, PTc, hbuf, s);
        }
        finalize_fb<<<Bdim, 256, 0, stream>>>(hbuf, outp);
    }
}

// Round 4
// 5144.326 us; speedup vs baseline: 3.4220x; 3.4220x over previous
//
#include <hip/hip_runtime.h>
#include <hip/hip_cooperative_groups.h>

namespace cg = cooperative_groups;

#define Bdim 640
#define Hdim 768
#define PJdim 256
#define Tdim 160
#define NSTEP (Tdim + 2)

typedef _Float16 half8 __attribute__((ext_vector_type(8)));
typedef float floatx4 __attribute__((ext_vector_type(4)));

// ---------------- workspace layout (halfs/bytes) ----------------
// h16:  [3][640][256] fp16 state   | zerop: 256B zeros
// m16:  [3][640][768] fp16 gate->proj handoff
// x16:  [160][640][40] fp16 pre-converted input
// Wfrag: per (l,ht): [kc16][g4][cf4][512] fragment-ordered gate weights
// Pfrag: per (l,cq4): [kc24][cg4][512] fragment-ordered proj weights
// cfb:  fallback c-state fp32
constexpr size_t HB_HALFS = 3ull * Bdim * PJdim;            // 491,520
constexpr size_t ZP_OFF   = HB_HALFS * 2;                   // byte offset
constexpr size_t MB_OFF   = ZP_OFF + 256;
constexpr size_t MB_HALFS = 3ull * Bdim * Hdim;             // 1,474,560
constexpr size_t X_OFF    = MB_OFF + MB_HALFS * 2;
constexpr size_t X_HALFS  = (size_t)Tdim * Bdim * 40;       // 4,096,000
constexpr size_t W_OFF    = X_OFF + X_HALFS * 2;
constexpr size_t W_HALFS  = 36ull * 131072;                 // 4,718,592
constexpr size_t P_OFF    = W_OFF + W_HALFS * 2;
constexpr size_t P_HALFS  = 3ull * 196608;                  // 589,824
constexpr size_t C_OFF    = P_OFF + P_HALFS * 2;
constexpr size_t C_BYTES  = 3ull * Bdim * Hdim * 4;

__device__ __forceinline__ float sigm(float v) { return 1.0f / (1.0f + __expf(-v)); }
__device__ __forceinline__ float tanh_fast(float v) { return 2.0f / (1.0f + __expf(-2.0f * v)) - 1.0f; }

// ---------------- one-time repack: fragment-ordered fp16 images ----------------
__global__ void repack_kernel(const float* __restrict__ x,
                              const float* __restrict__ W0, const float* __restrict__ W1,
                              const float* __restrict__ W2, const float* __restrict__ P0,
                              const float* __restrict__ P1, const float* __restrict__ P2,
                              _Float16* __restrict__ Wfrag, _Float16* __restrict__ Pfrag,
                              _Float16* __restrict__ x16)
{
    size_t idx = (size_t)blockIdx.x * 256 + threadIdx.x;
    if (idx < W_HALFS) {
        int slab = (int)(idx >> 17);          // /131072
        int l = slab / 12, ht = slab % 12;
        int r  = (int)(idx & 131071);
        int kc = r >> 13;                      // /8192
        int r2 = r & 8191;
        int g  = r2 >> 11;
        int cf = (r2 >> 9) & 3;
        int u  = r2 & 511;
        int lane = u >> 3, e = u & 7;
        int qd = lane >> 4, ln = lane & 15;
        int k   = kc * 32 + qd * 8 + e;
        int col = g * Hdim + ht * 64 + cf * 16 + ln;
        float v;
        if (l == 0)      v = (k < 296) ? W0[(size_t)k * 3072 + col] : 0.0f;
        else if (l == 1) v = W1[(size_t)k * 3072 + col];
        else             v = W2[(size_t)k * 3072 + col];
        Wfrag[idx] = (_Float16)v;
    } else if (idx < W_HALFS + P_HALFS) {
        size_t i = idx - W_HALFS;
        int l = (int)(i / 196608);
        int r = (int)(i % 196608);
        int cq = r / 49152;
        int r2 = r % 49152;
        int kc = r2 / 2048;
        int r3 = r2 & 2047;
        int cg = r3 >> 9;
        int u  = r3 & 511;
        int lane = u >> 3, e = u & 7;
        int qd = lane >> 4, ln = lane & 15;
        int k  = kc * 32 + qd * 8 + e;
        int pj = cq * 64 + cg * 16 + ln;
        const float* P = (l == 0) ? P0 : (l == 1) ? P1 : P2;
        Pfrag[i] = (_Float16)P[(size_t)k * PJdim + pj];
    } else if (idx < W_HALFS + P_HALFS + X_HALFS) {
        size_t i = idx - W_HALFS - P_HALFS;
        x16[i] = (_Float16)x[i];
    }
}

// ---------------- gate step body (one cell tile, one timestep) ----------------
// block: 128 rows x (4 gates x 64 hcols); 8 waves; wave (g=wv>>1, hh=wv&1) owns
// all 128 rows x 32 cols of gate g. Weights resident in Breg.
__device__ __forceinline__ void gate_step(
    int l, int b0r, int h0, int KC, int t,
    const half8 (&Breg)[16][2], float (&c)[8][2],
    const float (&bia)[2], const float (&bja)[2], const float (&bfa)[2], const float (&boa)[2],
    const _Float16* __restrict__ x16, const _Float16* __restrict__ h16,
    const _Float16* __restrict__ zerop, _Float16* __restrict__ mbuf,
    _Float16* __restrict__ Ast, float* __restrict__ zst, int tid)
{
    const int wv = tid >> 6, lane = tid & 63, qd = lane >> 4, ln = lane & 15;
    const int g = wv >> 1, hh = wv & 1;
    const int qd8 = qd * 8;
    const int rowg = b0r + wv * 16 + ln;                    // staging row for this lane

    const _Float16* xt  = x16 + ((size_t)t * Bdim + rowg) * 40;
    const _Float16* h0b = h16 + (size_t)rowg * PJdim - 40;                       // l==0, k in [40,296)
    const _Float16* lob = (l > 0) ? h16 + ((size_t)(l - 1) * Bdim + rowg) * PJdim : nullptr;
    const _Float16* hib = h16 + ((size_t)l * Bdim + rowg) * PJdim - 256;         // l>0, k>=256

    auto srcp = [&](int kc) -> const _Float16* {
        int k = kc * 32 + qd8;
        if (l == 0) return (k < 40) ? xt + k : (k < 296) ? h0b + k : zerop;
        return (k < 256) ? lob + k : hib + k;
    };

    floatx4 acc[8][2];
    const floatx4 fz = {0.f, 0.f, 0.f, 0.f};
#pragma unroll
    for (int i = 0; i < 8; ++i) { acc[i][0] = fz; acc[i][1] = fz; }

    uint4 pre = *(const uint4*)srcp(0);
#pragma unroll
    for (int kc = 0; kc < 16; ++kc) {
        if (kc < KC) {
            *(uint4*)(Ast + (size_t)(kc & 1) * 4096 + wv * 512 + lane * 8) = pre;
            if (kc + 1 < KC) pre = *(const uint4*)srcp(kc + 1);
            __syncthreads();
            const _Float16* Ab = Ast + (size_t)(kc & 1) * 4096;
#pragma unroll
            for (int rf = 0; rf < 8; ++rf) {
                half8 af = *(const half8*)(Ab + rf * 512 + lane * 8);
                acc[rf][0] = __builtin_amdgcn_mfma_f32_16x16x32_f16(af, Breg[kc][0], acc[rf][0], 0, 0, 0);
                acc[rf][1] = __builtin_amdgcn_mfma_f32_16x16x32_f16(af, Breg[kc][1], acc[rf][1], 0, 0, 0);
            }
        }
    }

    // elementwise: z through LDS in 8 row-passes of 16 rows
    const int trow = tid >> 5;            // 0..15
    const int hc0  = (tid * 2) & 63;      // even hcol
#pragma unroll
    for (int rf = 0; rf < 8; ++rf) {
        __syncthreads();                  // prev pass reads done (pass 0: gemm done per-wave; zst disjoint from Ast)
#pragma unroll
        for (int cf = 0; cf < 2; ++cf)
#pragma unroll
            for (int r = 0; r < 4; ++r)
                zst[(qd * 4 + r) * 256 + g * 64 + hh * 32 + cf * 16 + ln] = acc[rf][cf][r];
        __syncthreads();
        _Float16 mh[2];
#pragma unroll
        for (int j = 0; j < 2; ++j) {
            int hc = hc0 + j;
            float zi = zst[trow * 256 + hc]       + bia[j];
            float zj = zst[trow * 256 + 64 + hc]  + bja[j];
            float zf = zst[trow * 256 + 128 + hc] + bfa[j];
            float zo = zst[trow * 256 + 192 + hc] + boa[j];
            float cn = sigm(zf) * c[rf][j] + sigm(zi) * tanh_fast(zj);
            c[rf][j] = cn;
            mh[j] = (_Float16)(sigm(zo) * tanh_fast(cn));
        }
        union { _Float16 h2[2]; unsigned u; } pk;
        pk.h2[0] = mh[0]; pk.h2[1] = mh[1];
        int row_g = b0r + rf * 16 + trow;
        *(unsigned*)(mbuf + ((size_t)l * Bdim + row_g) * Hdim + h0 + hc0) = pk.u;
    }
}

// ---------------- proj step body: 128 rows x 64 pjcols, K=768, P in regs ----------------
__device__ __forceinline__ void proj_step(
    int l, int b0r, int cq, const half8 (&Preg)[24],
    const _Float16* __restrict__ mbuf, _Float16* __restrict__ h16,
    _Float16* __restrict__ Ast, int tid)
{
    const int wv = tid >> 6, lane = tid & 63, qd = lane >> 4, ln = lane & 15;
    const int rh = wv >> 2, cg = wv & 3;
    const int rowg = b0r + wv * 16 + ln;
    const _Float16* mrow = mbuf + ((size_t)l * Bdim + rowg) * Hdim + qd * 8;

    floatx4 pacc[4];
    const floatx4 fz = {0.f, 0.f, 0.f, 0.f};
#pragma unroll
    for (int i = 0; i < 4; ++i) pacc[i] = fz;

    uint4 pre = *(const uint4*)(mrow);
#pragma unroll
    for (int kc = 0; kc < 24; ++kc) {
        *(uint4*)(Ast + (size_t)(kc & 1) * 4096 + wv * 512 + lane * 8) = pre;
        if (kc < 23) pre = *(const uint4*)(mrow + (kc + 1) * 32);
        __syncthreads();
        const _Float16* Ab = Ast + (size_t)(kc & 1) * 4096;
#pragma unroll
        for (int rfl = 0; rfl < 4; ++rfl) {
            half8 af = *(const half8*)(Ab + (rh * 4 + rfl) * 512 + lane * 8);
            pacc[rfl] = __builtin_amdgcn_mfma_f32_16x16x32_f16(af, Preg[kc], pacc[rfl], 0, 0, 0);
        }
        __syncthreads();
    }
#pragma unroll
    for (int rfl = 0; rfl < 4; ++rfl)
#pragma unroll
        for (int r = 0; r < 4; ++r) {
            int row = b0r + (rh * 4 + rfl) * 16 + qd * 4 + r;
            h16[((size_t)l * Bdim + row) * PJdim + cq * 64 + cg * 16 + ln] = (_Float16)pacc[rfl][r];
        }
}

__device__ __forceinline__ void load_Breg(const _Float16* __restrict__ Wfrag, int l, int ht,
                                          int wv, int lane, half8 (&Breg)[16][2])
{
    const int g = wv >> 1, hh = wv & 1;
    const _Float16* wslab = Wfrag + ((size_t)(l * 12 + ht)) * 131072;
#pragma unroll
    for (int kc = 0; kc < 16; ++kc)
#pragma unroll
        for (int cf = 0; cf < 2; ++cf)
            Breg[kc][cf] = *(const half8*)(wslab + kc * 8192 + g * 2048 + (hh * 2 + cf) * 512 + lane * 8);
}

__device__ __forceinline__ void load_Preg(const _Float16* __restrict__ Pfrag, int l, int cq,
                                          int wv, int lane, half8 (&Preg)[24])
{
    const int cg = wv & 3;
    const _Float16* pslab = Pfrag + (size_t)l * 196608 + (size_t)cq * 49152;
#pragma unroll
    for (int kc = 0; kc < 24; ++kc)
        Preg[kc] = *(const half8*)(pslab + kc * 2048 + cg * 512 + lane * 8);
}

__device__ __forceinline__ void load_bias(const float* __restrict__ bias, int h0, int tid,
                                          float (&bia)[2], float (&bja)[2], float (&bfa)[2], float (&boa)[2])
{
    int hcg = h0 + ((tid * 2) & 63);
#pragma unroll
    for (int j = 0; j < 2; ++j) {
        bia[j] = bias[hcg + j];
        bja[j] = bias[Hdim + hcg + j];
        bfa[j] = bias[2 * Hdim + hcg + j] + 1.0f;   // forget bias folded
        boa[j] = bias[3 * Hdim + hcg + j];
    }
}

__device__ __forceinline__ void finalize_row(const _Float16* __restrict__ h16,
                                             float* __restrict__ out, int row, int lane)
{
    const _Float16* e = h16 + ((size_t)2 * Bdim + row) * PJdim + lane * 4;
    float v0 = (float)e[0], v1 = (float)e[1], v2 = (float)e[2], v3 = (float)e[3];
    float ss = v0 * v0 + v1 * v1 + v2 * v2 + v3 * v3;
#pragma unroll
    for (int o = 32; o > 0; o >>= 1) ss += __shfl_xor(ss, o, 64);
    float rs = rsqrtf(fmaxf(ss, 1e-12f));
    float4 o4; o4.x = v0 * rs; o4.y = v1 * rs; o4.z = v2 * rs; o4.w = v3 * rs;
    *(float4*)(out + (size_t)row * PJdim + lane * 4) = o4;
}

// ---------------- persistent cooperative kernel ----------------
__global__ __launch_bounds__(512)
void lstm_persist(const _Float16* __restrict__ x16, const _Float16* __restrict__ Wfrag,
                  const _Float16* __restrict__ Pfrag,
                  const float* __restrict__ bias0, const float* __restrict__ bias1,
                  const float* __restrict__ bias2,
                  _Float16* __restrict__ h16, _Float16* __restrict__ mbuf,
                  const _Float16* __restrict__ zerop, float* __restrict__ out)
{
    cg::grid_group grid = cg::this_grid();
    __shared__ __align__(16) _Float16 Ast[2 * 4096];
    __shared__ __align__(16) float zst[16 * 256];

    const int tid = threadIdx.x, bid = blockIdx.x;
    const int wv = tid >> 6, lane = tid & 63;

    // XCD-grouped role mapping: gid = bt2*3 + l lives on XCD gid>>1 (assuming bid%8=XCD)
    const int xcd = bid & 7, slot = bid >> 3;
    const int gid = xcd * 2 + (slot >> 4);
    const int rr  = slot & 15;
    const bool active = (gid < 15);
    const int bt2 = active ? gid / 3 : 0;
    const int l   = active ? gid % 3 : 0;
    const bool isgate = active && (rr < 12);
    const bool isproj = active && (rr >= 12);
    const int b0r = bt2 * 128;

    if (isgate) {
        const int ht = rr, h0 = ht * 64;
        const int KC = (l == 0) ? 10 : 16;
        half8 Breg[16][2];
        load_Breg(Wfrag, l, ht, wv, lane, Breg);
        float bia[2], bja[2], bfa[2], boa[2];
        load_bias((l == 0) ? bias0 : (l == 1) ? bias1 : bias2, h0, tid, bia, bja, bfa, boa);
        float c[8][2];
#pragma unroll
        for (int i = 0; i < 8; ++i) { c[i][0] = 0.f; c[i][1] = 0.f; }
        for (int s = 0; s < NSTEP; ++s) {
            const int t = s - l;
            if (t >= 0 && t < Tdim)
                gate_step(l, b0r, h0, KC, t, Breg, c, bia, bja, bfa, boa,
                          x16, h16, zerop, mbuf, Ast, zst, tid);
            grid.sync();
            grid.sync();
        }
    } else if (isproj) {
        const int cq = rr - 12;
        half8 Preg[24];
        load_Preg(Pfrag, l, cq, wv, lane, Preg);
        for (int s = 0; s < NSTEP; ++s) {
            grid.sync();
            const int tp = s - l;
            if (tp >= 0 && tp < Tdim)
                proj_step(l, b0r, cq, Preg, mbuf, h16, Ast, tid);
            grid.sync();
        }
    } else {
        for (int s = 0; s < NSTEP; ++s) { grid.sync(); grid.sync(); }
    }

    if (bid < 80) {
        int row = bid * 8 + wv;
        finalize_row(h16, out, row, lane);
    }
}

// ---------------- fallback: per-step kernels, c-state in global ----------------
__global__ __launch_bounds__(512)
void gate_fb(const _Float16* __restrict__ x16, const _Float16* __restrict__ Wfrag,
             const float* __restrict__ bias0, const float* __restrict__ bias1,
             const float* __restrict__ bias2,
             _Float16* __restrict__ h16, _Float16* __restrict__ mbuf,
             const _Float16* __restrict__ zerop, float* __restrict__ cfb, int s)
{
    __shared__ __align__(16) _Float16 Ast[2 * 4096];
    __shared__ __align__(16) float zst[16 * 256];
    const int tid = threadIdx.x, bid = blockIdx.x;
    const int ht = bid % 12, z = bid / 12, l = z % 3, bt2 = z / 3;
    const int t = s - l;
    if (t < 0 || t >= Tdim) return;
    const int wv = tid >> 6, lane = tid & 63;
    const int b0r = bt2 * 128, h0 = ht * 64;
    const int KC = (l == 0) ? 10 : 16;
    half8 Breg[16][2];
    load_Breg(Wfrag, l, ht, wv, lane, Breg);
    float bia[2], bja[2], bfa[2], boa[2];
    load_bias((l == 0) ? bias0 : (l == 1) ? bias1 : bias2, h0, tid, bia, bja, bfa, boa);
    const int trow = tid >> 5, hc0 = (tid * 2) & 63;
    float c[8][2];
#pragma unroll
    for (int rf = 0; rf < 8; ++rf)
#pragma unroll
        for (int j = 0; j < 2; ++j)
            c[rf][j] = cfb[((size_t)l * Bdim + b0r + rf * 16 + trow) * Hdim + h0 + hc0 + j];
    gate_step(l, b0r, h0, KC, t, Breg, c, bia, bja, bfa, boa, x16, h16, zerop, mbuf, Ast, zst, tid);
#pragma unroll
    for (int rf = 0; rf < 8; ++rf)
#pragma unroll
        for (int j = 0; j < 2; ++j)
            cfb[((size_t)l * Bdim + b0r + rf * 16 + trow) * Hdim + h0 + hc0 + j] = c[rf][j];
}

__global__ __launch_bounds__(512)
void proj_fb(const _Float16* __restrict__ Pfrag, const _Float16* __restrict__ mbuf,
             _Float16* __restrict__ h16, int s)
{
    __shared__ __align__(16) _Float16 Ast[2 * 4096];
    const int tid = threadIdx.x, bid = blockIdx.x;
    const int cq = bid & 3, z = bid >> 2, l = z % 3, bt2 = z / 3;
    const int tp = s - l;
    if (tp < 0 || tp >= Tdim) return;
    const int wv = tid >> 6, lane = tid & 63;
    half8 Preg[24];
    load_Preg(Pfrag, l, cq, wv, lane, Preg);
    proj_step(l, bt2 * 128, cq, Preg, mbuf, h16, Ast, tid);
}

__global__ __launch_bounds__(512)
void fin_fb(const _Float16* __restrict__ h16, float* __restrict__ out)
{
    int row = blockIdx.x * 8 + (threadIdx.x >> 6);
    finalize_row(h16, out, row, threadIdx.x & 63);
}

extern "C" void kernel_launch(void* const* d_in, const int* in_sizes, int n_in,
                              void* d_out, int out_size, void* d_ws, size_t ws_size,
                              hipStream_t stream)
{
    (void)in_sizes; (void)n_in; (void)out_size; (void)ws_size;
    const float* x  = (const float*)d_in[0];
    const float* W0 = (const float*)d_in[1];
    const float* b0 = (const float*)d_in[2];
    const float* P0 = (const float*)d_in[3];
    const float* W1 = (const float*)d_in[4];
    const float* b1 = (const float*)d_in[5];
    const float* P1 = (const float*)d_in[6];
    const float* W2 = (const float*)d_in[7];
    const float* b2 = (const float*)d_in[8];
    const float* P2 = (const float*)d_in[9];

    char* ws = (char*)d_ws;
    _Float16* h16   = (_Float16*)(ws);
    _Float16* zerop = (_Float16*)(ws + ZP_OFF);
    _Float16* mbuf  = (_Float16*)(ws + MB_OFF);
    _Float16* x16   = (_Float16*)(ws + X_OFF);
    _Float16* Wfrag = (_Float16*)(ws + W_OFF);
    _Float16* Pfrag = (_Float16*)(ws + P_OFF);
    float*    cfb   = (float*)(ws + C_OFF);
    float*    outp  = (float*)d_out;

    // zero h state + zero page (+ fallback c)
    hipMemsetAsync(ws, 0, ZP_OFF + 256, stream);
    hipMemsetAsync(cfb, 0, C_BYTES, stream);

    {
        constexpr size_t total = W_HALFS + P_HALFS + X_HALFS;
        int grid = (int)((total + 255) / 256);
        repack_kernel<<<grid, 256, 0, stream>>>(x, W0, W1, W2, P0, P1, P2, Wfrag, Pfrag, x16);
    }

    int occ = 0;
    hipError_t oe = hipOccupancyMaxActiveBlocksPerMultiprocessor(&occ, lstm_persist, 512, 0);
    bool coop = (oe == hipSuccess && occ >= 1);
    if (coop) {
        void* args[] = { (void*)&x16, (void*)&Wfrag, (void*)&Pfrag,
                         (void*)&b0, (void*)&b1, (void*)&b2,
                         (void*)&h16, (void*)&mbuf, (void*)&zerop, (void*)&outp };
        hipError_t le = hipLaunchCooperativeKernel((const void*)lstm_persist,
                                                   dim3(256), dim3(512), args, 0, stream);
        if (le != hipSuccess) { (void)hipGetLastError(); coop = false; }
    }
    if (!coop) {
        for (int s = 0; s < NSTEP; ++s) {
            gate_fb<<<180, 512, 0, stream>>>(x16, Wfrag, b0, b1, b2, h16, mbuf, zerop, cfb, s);
            proj_fb<<<60, 512, 0, stream>>>(Pfrag, mbuf, h16, s);
        }
        fin_fb<<<80, 512, 0, stream>>>(h16, outp);
    }
}